// Round 12
// baseline (1843.104 us; speedup 1.0000x reference)
//
#include <hip/hip_runtime.h>

// MultiHeadAttentionCell: B=2, L=2048, H=16, C=64, fp32 in/out.
// Outputs (concat in d_out): context_vec (B,L,H*C)=4194304 | scores (B,H,L,L)=134217728 | attn (B,H,L,L)=134217728
// scores = Q K^T + edge ; attn = softmax(where(mask, scores/8, -1e18)) * mask ; ctx = attn @ V
//
// Round 12: b-PAIR FUSION (edge is b-independent; R11 counters showed edge reads
// ~1.07GB = the entire FETCH excess). Block = (h, 32-row i-tile) x BOTH batches:
// waves 0,1 -> b=0, waves 2,3 -> b=1, same rows -> edge loads dedup in-block.
// Structural edge traffic halves (1.07GB -> 536MB). nt stores REVERTED (R11:
// WRITE inflated 1.078->1.292GB; L2 write-allocate was already coalescing).
// Phase A: per-b K double-buffer, 1 barrier/iter, writes sc + row-sums l.
// Phase B: recompute QK^T (bitwise-identical), attn=p/l once, PV -> ctx.
// K/V at-stage loads in B + mask at-use (VGPR<=128 at 4 blocks/CU, LDS=40KB exact).
// Raw lgkmcnt-only barriers; XCD chunk swizzle (2 heads/XCD -> K/V L2-resident).
// No max-subtraction: scores/8 ~ N(0,1)+edge/8, exp() safe in fp32.

typedef __attribute__((ext_vector_type(8))) short bf16x8;  // 8 bf16 = 4 VGPRs
typedef __attribute__((ext_vector_type(4))) float f32x4;
typedef __attribute__((ext_vector_type(4))) int   i32x4;

#define LQ 2048
#define NH 16
#define CD 64
#define NHC (NH*CD)

__device__ inline short f2bf(float x) {
    union { float f; unsigned u; } v; v.f = x;
    unsigned r = v.u + 0x7FFFu + ((v.u >> 16) & 1u);   // RTNE
    return (short)(r >> 16);
}

__device__ inline bf16x8 pack8(f32x4 a, f32x4 b) {
    bf16x8 r;
    r[0] = f2bf(a[0]); r[1] = f2bf(a[1]); r[2] = f2bf(a[2]); r[3] = f2bf(a[3]);
    r[4] = f2bf(b[0]); r[5] = f2bf(b[1]); r[6] = f2bf(b[2]); r[7] = f2bf(b[3]);
    return r;
}

// LDS-visibility barrier WITHOUT __syncthreads' vmcnt(0) drain.
__device__ inline void lds_barrier() {
    asm volatile("s_waitcnt lgkmcnt(0)" ::: "memory");
    __builtin_amdgcn_s_barrier();
}

// XOR-swizzled address inside a [rows][64]-short tile (128 B rows).
#define SWZ(base, row, bytecol) \
    ((char*)(base) + ((row) * 128) + ((bytecol) ^ (((row) & 7) << 4)))

// LDS map (40960 B total = 4 blocks/CU x 40KB = 160KB exact):
//   phase A: K dbuf slot s, batch bb at  (s*2+bb)*8192        (32 KB)
//   phase B: K[bb] at bb*8192 ; V[bb] at 16384 + bb*8192      (32 KB)
//   Wt per wave: 32768 + wave*2048                            (8 KB)

// grid: 1024 (XCD-swizzled -> 64 i-tiles x 16 h), block 256 (4 waves).
__global__ __launch_bounds__(256, 4)
void k_attn(const float* __restrict__ q, const float* __restrict__ kk,
            const float* __restrict__ v, const int* __restrict__ mask,
            const float* __restrict__ edge,
            float* __restrict__ sc, float* __restrict__ attn,
            float* __restrict__ ctx)
{
    __shared__ __align__(16) char lds[40960];

    // XCD-chunk swizzle (bijective, 1024 % 8 == 0): XCD x owns heads {2x,2x+1},
    // all 64 i-tiles -> per-XCD K/V working set (2h x 2b x 1MB) = 4MB = its L2.
    const int flat = blockIdx.x;
    const int L = (flat & 7) * 128 + (flat >> 3);
    const int h = L >> 6;
    const int i0 = (L & 63) * 32;

    const int tid = threadIdx.x;
    const int r = tid >> 2, seg = (tid & 3) * 16;   // K-staging mapping
    const int rgrp = tid >> 4, c4 = tid & 15;       // V-staging mapping (4x4 micro-tile)
    const int wave = tid >> 6, lane = tid & 63;
    const int quad = lane >> 4, mm = lane & 15;
    const int wb = wave >> 1;                       // this wave's batch
    const int wr = wave & 1;                        // row half (0: i0.., 1: i0+16..)

    char* const wtb = lds + 32768 + wave * 2048;

    const int gi = i0 + wr * 16 + mm;               // this lane's query row
    // Q as B-fragment: B[k=quad*8+t][n=mm] = Q[gi][k]
    const float* qp = q + ((size_t)((wb * LQ + gi) * NH + h)) * CD;
    bf16x8 qa0 = pack8(*(const f32x4*)(qp + quad * 8), *(const f32x4*)(qp + quad * 8 + 4));
    bf16x8 qa1 = pack8(*(const f32x4*)(qp + 32 + quad * 8), *(const f32x4*)(qp + 32 + quad * 8 + 4));

    const float* erow = edge + ((size_t)(h * LQ + gi)) * LQ;       // b-independent!
    const int*   mrow = mask + ((size_t)(wb * LQ + gi)) * LQ;
    const size_t srow = ((size_t)((wb * NH + h) * LQ + gi)) * LQ;  // sc/attn row base

    // staging pointers (all 256 threads stage BOTH batches' tiles)
    const float* k0p = kk + ((size_t)(r * NH + h)) * CD + seg;
    const float* k1p = k0p + (size_t)LQ * NHC;
    const float* v0p = v + ((size_t)((rgrp * 4) * NH + h)) * CD + c4 * 4;
    const float* v1p = v0p + (size_t)LQ * NHC;
    const size_t kstep = (size_t)64 * NHC;

    // ================= Phase A: row sums + sc =================
    f32x4 ev[4];
    #pragma unroll
    for (int jt = 0; jt < 4; ++jt)
        ev[jt] = *(const f32x4*)(erow + jt * 16 + quad * 4);

    f32x4 kr0[4], kr1[4];
    #pragma unroll
    for (int u = 0; u < 4; ++u) { kr0[u] = ((const f32x4*)k0p)[u]; kr1[u] = ((const f32x4*)k1p)[u]; }
    #pragma unroll
    for (int u = 0; u < 4; ++u) {   // stage jb=0 into slot 0 (both b)
        *(short4*)SWZ(lds, r, 2 * seg + 8 * u) =
            make_short4(f2bf(kr0[u][0]), f2bf(kr0[u][1]), f2bf(kr0[u][2]), f2bf(kr0[u][3]));
        *(short4*)SWZ(lds + 8192, r, 2 * seg + 8 * u) =
            make_short4(f2bf(kr1[u][0]), f2bf(kr1[u][1]), f2bf(kr1[u][2]), f2bf(kr1[u][3]));
    }
    #pragma unroll
    for (int u = 0; u < 4; ++u) {   // issue jb=1
        kr0[u] = ((const f32x4*)(k0p + kstep))[u];
        kr1[u] = ((const f32x4*)(k1p + kstep))[u];
    }
    lds_barrier();

    float lacc = 0.f;
    for (int jb = 0; jb < 32; ++jb) {
        const int j0 = jb * 64;
        const int cur = jb & 1;
        if (jb < 31) {   // stage next slot (both b); issue jb+2
            char* kn0 = lds + ((cur ^ 1) * 2) * 8192;
            char* kn1 = kn0 + 8192;
            #pragma unroll
            for (int u = 0; u < 4; ++u) {
                *(short4*)SWZ(kn0, r, 2 * seg + 8 * u) =
                    make_short4(f2bf(kr0[u][0]), f2bf(kr0[u][1]), f2bf(kr0[u][2]), f2bf(kr0[u][3]));
                *(short4*)SWZ(kn1, r, 2 * seg + 8 * u) =
                    make_short4(f2bf(kr1[u][0]), f2bf(kr1[u][1]), f2bf(kr1[u][2]), f2bf(kr1[u][3]));
            }
            if (jb < 30) {
                const float* a0 = k0p + kstep * (jb + 2);
                const float* a1 = k1p + kstep * (jb + 2);
                #pragma unroll
                for (int u = 0; u < 4; ++u) { kr0[u] = ((const f32x4*)a0)[u]; kr1[u] = ((const f32x4*)a1)[u]; }
            }
        }
        // swapped QK^T from this wave's batch tile
        char* const kb = lds + (cur * 2 + wb) * 8192;
        f32x4 acc[4];
        #pragma unroll
        for (int jt = 0; jt < 4; ++jt) {
            bf16x8 kf0 = *(const bf16x8*)SWZ(kb, jt * 16 + mm, 16 * quad);
            bf16x8 kf1 = *(const bf16x8*)SWZ(kb, jt * 16 + mm, 64 + 16 * quad);
            f32x4 a = {0.f, 0.f, 0.f, 0.f};
            a = __builtin_amdgcn_mfma_f32_16x16x32_bf16(kf0, qa0, a, 0, 0, 0);
            a = __builtin_amdgcn_mfma_f32_16x16x32_bf16(kf1, qa1, a, 0, 0, 0);
            acc[jt] = a;
        }
        #pragma unroll
        for (int jt = 0; jt < 4; ++jt) {
            i32x4 m = *(const i32x4*)(mrow + j0 + jt * 16 + quad * 4);   // at-use (L2-hot)
            f32x4 s4 = acc[jt] + ev[jt];
            *(f32x4*)(sc + srow + j0 + jt * 16 + quad * 4) = s4;
            lacc += (m[0] ? __expf(s4[0] * 0.125f) : 0.f)
                  + (m[1] ? __expf(s4[1] * 0.125f) : 0.f)
                  + (m[2] ? __expf(s4[2] * 0.125f) : 0.f)
                  + (m[3] ? __expf(s4[3] * 0.125f) : 0.f);
        }
        if (jb < 31) {
            #pragma unroll
            for (int jt = 0; jt < 4; ++jt)
                ev[jt] = *(const f32x4*)(erow + j0 + 64 + jt * 16 + quad * 4);
        }
        lds_barrier();   // dbuf: one barrier covers "next staged" + "cur reads done"
    }

    // row total over the 4 quads sharing this mm
    lacc += __shfl_xor(lacc, 16, 64);
    lacc += __shfl_xor(lacc, 32, 64);
    const float inv = (lacc > 0.f) ? 1.f / lacc : 0.f;   // l==0 iff all-masked row -> 0

    // ================= Phase B: attn (normalized) + PV =================
    #pragma unroll
    for (int jt = 0; jt < 4; ++jt)
        ev[jt] = *(const f32x4*)(erow + jt * 16 + quad * 4);
    f32x4 cacc[4] = { {0,0,0,0}, {0,0,0,0}, {0,0,0,0}, {0,0,0,0} };

    for (int jb = 0; jb < 32; ++jb) {
        const int j0 = jb * 64;
        // at-stage loads (short-lived regs; K/V are L2-resident on this XCD)
        {
            const float* a0 = k0p + kstep * jb;
            const float* a1 = k1p + kstep * jb;
            const float* b0 = v0p + kstep * jb;
            const float* b1 = v1p + kstep * jb;
            f32x4 ka[4], kb4[4], va[4], vb4[4];
            #pragma unroll
            for (int u = 0; u < 4; ++u) { ka[u] = ((const f32x4*)a0)[u]; kb4[u] = ((const f32x4*)a1)[u]; }
            #pragma unroll
            for (int t = 0; t < 4; ++t) { va[t] = *(const f32x4*)(b0 + t * NHC); vb4[t] = *(const f32x4*)(b1 + t * NHC); }
            #pragma unroll
            for (int u = 0; u < 4; ++u) {
                *(short4*)SWZ(lds, r, 2 * seg + 8 * u) =
                    make_short4(f2bf(ka[u][0]), f2bf(ka[u][1]), f2bf(ka[u][2]), f2bf(ka[u][3]));
                *(short4*)SWZ(lds + 8192, r, 2 * seg + 8 * u) =
                    make_short4(f2bf(kb4[u][0]), f2bf(kb4[u][1]), f2bf(kb4[u][2]), f2bf(kb4[u][3]));
            }
            #pragma unroll
            for (int cs = 0; cs < 4; ++cs) {
                *(short4*)SWZ(lds + 16384, c4 * 4 + cs, 8 * rgrp) =
                    make_short4(f2bf(va[0][cs]), f2bf(va[1][cs]), f2bf(va[2][cs]), f2bf(va[3][cs]));
                *(short4*)SWZ(lds + 24576, c4 * 4 + cs, 8 * rgrp) =
                    make_short4(f2bf(vb4[0][cs]), f2bf(vb4[1][cs]), f2bf(vb4[2][cs]), f2bf(vb4[3][cs]));
            }
        }
        lds_barrier();

        char* const kb = lds + wb * 8192;
        f32x4 acc[4];                  // identical MFMA as phase A -> bitwise-same s4
        #pragma unroll
        for (int jt = 0; jt < 4; ++jt) {
            bf16x8 kf0 = *(const bf16x8*)SWZ(kb, jt * 16 + mm, 16 * quad);
            bf16x8 kf1 = *(const bf16x8*)SWZ(kb, jt * 16 + mm, 64 + 16 * quad);
            f32x4 a = {0.f, 0.f, 0.f, 0.f};
            a = __builtin_amdgcn_mfma_f32_16x16x32_bf16(kf0, qa0, a, 0, 0, 0);
            a = __builtin_amdgcn_mfma_f32_16x16x32_bf16(kf1, qa1, a, 0, 0, 0);
            acc[jt] = a;
        }

        // epilogue: attn = normalized w (normal stores), Wt = bf16(w) for PV
        #pragma unroll
        for (int jt = 0; jt < 4; ++jt) {
            i32x4 m = *(const i32x4*)(mrow + j0 + jt * 16 + quad * 4);
            f32x4 s4 = acc[jt] + ev[jt];
            f32x4 w;
            w[0] = m[0] ? __expf(s4[0] * 0.125f) * inv : 0.f;
            w[1] = m[1] ? __expf(s4[1] * 0.125f) * inv : 0.f;
            w[2] = m[2] ? __expf(s4[2] * 0.125f) * inv : 0.f;
            w[3] = m[3] ? __expf(s4[3] * 0.125f) * inv : 0.f;
            *(f32x4*)(attn + srow + j0 + jt * 16 + quad * 4) = w;
            *(short4*)SWZ(wtb, mm, 32 * jt + 8 * quad) =
                make_short4(f2bf(w[0]), f2bf(w[1]), f2bf(w[2]), f2bf(w[3]));
        }

        if (jb < 31) {
            #pragma unroll
            for (int jt = 0; jt < 4; ++jt)
                ev[jt] = *(const f32x4*)(erow + j0 + 64 + jt * 16 + quad * 4);
        }

        // PV: A = Wt row mm (wave-internal RAW), B = V[wb].
        char* const vb = lds + 16384 + wb * 8192;
        #pragma unroll
        for (int kt = 0; kt < 2; ++kt) {
            bf16x8 aw = *(const bf16x8*)SWZ(wtb, mm, 64 * kt + 16 * quad);
            #pragma unroll
            for (int nt = 0; nt < 4; ++nt) {
                bf16x8 bbv = *(const bf16x8*)SWZ(vb, nt * 16 + mm, 64 * kt + 16 * quad);
                cacc[nt] = __builtin_amdgcn_mfma_f32_16x16x32_bf16(aw, bbv, cacc[nt], 0, 0, 0);
            }
        }
        lds_barrier();                 // readers done; next iter may overwrite
    }

    // ctx: C-layout (col c = nt*16+mm, row i = quad*4+reg); already normalized
    const int irow = i0 + wr * 16 + quad * 4;
    #pragma unroll
    for (int nt = 0; nt < 4; ++nt) {
        const int c = nt * 16 + mm;
        #pragma unroll
        for (int reg = 0; reg < 4; ++reg) {
            const int i = irow + reg;
            ctx[((size_t)(wb * LQ + i)) * NHC + h * CD + c] = cacc[nt][reg];
        }
    }
}

extern "C" void kernel_launch(void* const* d_in, const int* in_sizes, int n_in,
                              void* d_out, int out_size, void* d_ws, size_t ws_size,
                              hipStream_t stream) {
    const float* q    = (const float*)d_in[0];
    const float* k    = (const float*)d_in[1];
    const float* v    = (const float*)d_in[2];
    const int*   mask = (const int*)d_in[3];    // bool -> int32 per harness contract
    const float* edge = (const float*)d_in[4];

    float* out = (float*)d_out;
    float* ctx = out;                            // 2*2048*1024
    float* sc  = out + 4194304;                  // scores (B,H,L,L)
    float* at  = sc + 134217728;                 // attn   (B,H,L,L)

    k_attn<<<dim3(1024), 256, 0, stream>>>(q, k, v, mask, edge, sc, at, ctx);
}

// Round 13
// 1671.887 us; speedup vs baseline: 1.1024x; 1.1024x over previous
//
#include <hip/hip_runtime.h>

// MultiHeadAttentionCell: B=2, L=2048, H=16, C=64, fp32 in/out.
// Outputs (concat in d_out): context_vec (B,L,H*C)=4194304 | scores (B,H,L,L)=134217728 | attn (B,H,L,L)=134217728
// scores = Q K^T + edge ; attn = softmax(where(mask, scores/8, -1e18)) * mask ; ctx = attn @ V
//
// Round 13: R10 structure with 512-thread b-PAIR blocks + EXPLICIT edge LDS sharing.
// R10 counters: FETCH 1.11GB, of which edge = 1.07GB (4x its 268MB: x2 phases x2 b).
// R12 proved cache-level dedup of duplicate loads does NOT happen -> stage edge in LDS
// once per block; waves 0-3 (b=0) and 4-7 (b=1) read the same tile. Edge -> 536MB total.
// Everything else is R10: K dbuf 1-barrier phase A; 2-barrier phase B; reg prefetch
// K/V/edge 1-2 tiles ahead; mask 1-ahead in regs; V scalar-transpose staging; normal
// stores (R11: nt inflated WRITE); raw lgkmcnt-only barriers; XCD chunk swizzle.
// LDS 66KB -> 2 blocks/CU = 16 waves/CU (same occupancy as R10). Grid 512 = 1 pass.
// No max-subtraction: scores/8 ~ N(0,1)+edge/8, exp() safe in fp32.

typedef __attribute__((ext_vector_type(8))) short bf16x8;  // 8 bf16 = 4 VGPRs
typedef __attribute__((ext_vector_type(4))) float f32x4;
typedef __attribute__((ext_vector_type(4))) int   i32x4;

#define LQ 2048
#define NH 16
#define CD 64
#define NHC (NH*CD)

__device__ inline short f2bf(float x) {
    union { float f; unsigned u; } v; v.f = x;
    unsigned r = v.u + 0x7FFFu + ((v.u >> 16) & 1u);   // RTNE
    return (short)(r >> 16);
}

__device__ inline bf16x8 pack8(f32x4 a, f32x4 b) {
    bf16x8 r;
    r[0] = f2bf(a[0]); r[1] = f2bf(a[1]); r[2] = f2bf(a[2]); r[3] = f2bf(a[3]);
    r[4] = f2bf(b[0]); r[5] = f2bf(b[1]); r[6] = f2bf(b[2]); r[7] = f2bf(b[3]);
    return r;
}

// LDS-visibility barrier WITHOUT __syncthreads' vmcnt(0) drain.
__device__ inline void lds_barrier() {
    asm volatile("s_waitcnt lgkmcnt(0)" ::: "memory");
    __builtin_amdgcn_s_barrier();
}

// XOR-swizzled address inside a [rows][64]-short bf16 tile (128 B rows).
#define SWZ(base, row, bytecol) \
    ((char*)(base) + ((row) * 128) + ((bytecol) ^ (((row) & 7) << 4)))

// LDS map (67584 B total -> 2 blocks/CU):
//  region1 [0,32768):
//    phase A: K dbuf slot s, batch bb at (s*2+bb)*8192   (bf16 [64][64] swizzled)
//    phase B: K[bb] at bb*8192 ; V[bb] at 16384+bb*8192  (V^T bf16 [64][64] swizzled)
//  region2 [32768, 32768+2*17408):
//    phase A: edge f32 dbuf: slot s at 32768 + s*17408   ([64][68] f32, 16B rowstart)
//    phase B: edge slot0 ; Wt per wave at 50176 + wave*2048 ([16][64] bf16 swizzled)
#define EDGE_LDS(s) (lds + 32768 + (s) * 17408)
#define EDGE_AT(base, row, colf32) ((float*)(base) + (row) * 68 + (colf32))

// grid: 512 (XCD-swizzled -> 32 i-tiles x 16 h), block 512 (8 waves: 4 per batch).
__global__ __launch_bounds__(512, 4)
void k_attn(const float* __restrict__ q, const float* __restrict__ kk,
            const float* __restrict__ v, const int* __restrict__ mask,
            const float* __restrict__ edge,
            float* __restrict__ sc, float* __restrict__ attn,
            float* __restrict__ ctx)
{
    __shared__ __align__(16) char lds[67584];

    // XCD-chunk swizzle (bijective, 512 % 8 == 0): XCD x owns 64 consecutive L = 2 heads.
    const int flat = blockIdx.x;
    const int L = (flat & 7) * 64 + (flat >> 3);
    const int h = L >> 5;
    const int i0 = (L & 31) * 64;

    const int tid = threadIdx.x;
    const int bb = tid >> 8;                        // staging half: which batch this thread stages
    const int tt = tid & 255;
    const int r = tt >> 2, seg = (tt & 3) * 16;     // K/V staging mapping (per 256-half)
    const int erow_st = tid >> 3, ecol_st = (tid & 7) * 8;  // edge staging mapping (512 thr)
    const int wave = tid >> 6, lane = tid & 63;
    const int quad = lane >> 4, mm = lane & 15;
    const int wb = wave >> 2;                       // this wave's batch
    const int wrow = wave & 3;                      // row group (16 rows each)

    char* const wtb = lds + 50176 + wave * 2048;

    const int gi = i0 + wrow * 16 + mm;             // this lane's query row
    // Q as B-fragment: B[k=quad*8+t][n=mm] = Q[gi][k]
    const float* qp = q + ((size_t)((wb * LQ + gi) * NH + h)) * CD;
    bf16x8 qa0 = pack8(*(const f32x4*)(qp + quad * 8), *(const f32x4*)(qp + quad * 8 + 4));
    bf16x8 qa1 = pack8(*(const f32x4*)(qp + 32 + quad * 8), *(const f32x4*)(qp + 32 + quad * 8 + 4));

    const int*   mrow = mask + ((size_t)(wb * LQ + gi)) * LQ;
    const size_t srow = ((size_t)((wb * NH + h) * LQ + gi)) * LQ;   // sc/attn row base

    // staging pointers
    const float* kst = kk + (size_t)bb * LQ * NHC + ((size_t)(r * NH + h)) * CD + seg;
    const float* vst = v  + (size_t)bb * LQ * NHC + ((size_t)(r * NH + h)) * CD + seg;
    const float* est = edge + ((size_t)(h * LQ + i0 + erow_st)) * LQ + ecol_st;
    const size_t kstep = (size_t)64 * NHC;

    // ================= Phase A: row sums + sc =================
    // prologue: stage jb=0 (K both b via halves + edge), prefetch jb=1 regs
    f32x4 kr[4], er0, er1;
    #pragma unroll
    for (int u = 0; u < 4; ++u) kr[u] = ((const f32x4*)kst)[u];
    er0 = *(const f32x4*)est; er1 = *(const f32x4*)(est + 4);
    {
        char* kb = lds + bb * 8192;                 // slot0
        #pragma unroll
        for (int u = 0; u < 4; ++u)
            *(short4*)SWZ(kb, r, 2 * seg + 8 * u) =
                make_short4(f2bf(kr[u][0]), f2bf(kr[u][1]), f2bf(kr[u][2]), f2bf(kr[u][3]));
        *(f32x4*)EDGE_AT(EDGE_LDS(0), erow_st, ecol_st) = er0;
        *(f32x4*)EDGE_AT(EDGE_LDS(0), erow_st, ecol_st + 4) = er1;
    }
    #pragma unroll
    for (int u = 0; u < 4; ++u) kr[u] = ((const f32x4*)(kst + kstep))[u];
    er0 = *(const f32x4*)(est + 64); er1 = *(const f32x4*)(est + 68);

    i32x4 mv[4];
    #pragma unroll
    for (int jt = 0; jt < 4; ++jt)
        mv[jt] = *(const i32x4*)(mrow + jt * 16 + quad * 4);

    lds_barrier();

    float lacc = 0.f;
    for (int jb = 0; jb < 32; ++jb) {
        const int j0 = jb * 64;
        const int cur = jb & 1;
        if (jb < 31) {   // stage next slot from regs; issue jb+2 loads
            char* kn = lds + ((cur ^ 1) * 2 + bb) * 8192;
            #pragma unroll
            for (int u = 0; u < 4; ++u)
                *(short4*)SWZ(kn, r, 2 * seg + 8 * u) =
                    make_short4(f2bf(kr[u][0]), f2bf(kr[u][1]), f2bf(kr[u][2]), f2bf(kr[u][3]));
            *(f32x4*)EDGE_AT(EDGE_LDS(cur ^ 1), erow_st, ecol_st) = er0;
            *(f32x4*)EDGE_AT(EDGE_LDS(cur ^ 1), erow_st, ecol_st + 4) = er1;
            if (jb < 30) {
                const float* kp = kst + kstep * (jb + 2);
                #pragma unroll
                for (int u = 0; u < 4; ++u) kr[u] = ((const f32x4*)kp)[u];
                er0 = *(const f32x4*)(est + (size_t)(jb + 2) * 64);
                er1 = *(const f32x4*)(est + (size_t)(jb + 2) * 64 + 4);
            }
        }
        // swapped QK^T from this wave's batch tile
        char* const kb = lds + (cur * 2 + wb) * 8192;
        f32x4 acc[4];
        #pragma unroll
        for (int jt = 0; jt < 4; ++jt) {
            bf16x8 kf0 = *(const bf16x8*)SWZ(kb, jt * 16 + mm, 16 * quad);
            bf16x8 kf1 = *(const bf16x8*)SWZ(kb, jt * 16 + mm, 64 + 16 * quad);
            f32x4 a = {0.f, 0.f, 0.f, 0.f};
            a = __builtin_amdgcn_mfma_f32_16x16x32_bf16(kf0, qa0, a, 0, 0, 0);
            a = __builtin_amdgcn_mfma_f32_16x16x32_bf16(kf1, qa1, a, 0, 0, 0);
            acc[jt] = a;
        }
        // epilogue: edge from LDS (shared by both b-halves), sc store, running sum
        char* const eb = EDGE_LDS(cur);
        #pragma unroll
        for (int jt = 0; jt < 4; ++jt) {
            f32x4 ev = *(const f32x4*)EDGE_AT(eb, wrow * 16 + mm, jt * 16 + quad * 4);
            f32x4 s4 = acc[jt] + ev;
            *(f32x4*)(sc + srow + j0 + jt * 16 + quad * 4) = s4;
            lacc += (mv[jt][0] ? __expf(s4[0] * 0.125f) : 0.f)
                  + (mv[jt][1] ? __expf(s4[1] * 0.125f) : 0.f)
                  + (mv[jt][2] ? __expf(s4[2] * 0.125f) : 0.f)
                  + (mv[jt][3] ? __expf(s4[3] * 0.125f) : 0.f);
        }
        if (jb < 31) {   // mask 1-ahead
            #pragma unroll
            for (int jt = 0; jt < 4; ++jt)
                mv[jt] = *(const i32x4*)(mrow + j0 + 64 + jt * 16 + quad * 4);
        }
        lds_barrier();   // dbuf: one barrier covers "next staged" + "cur reads done"
    }

    // row total over the 4 quads sharing this mm
    lacc += __shfl_xor(lacc, 16, 64);
    lacc += __shfl_xor(lacc, 32, 64);
    const float inv = (lacc > 0.f) ? 1.f / lacc : 0.f;   // l==0 iff all-masked row -> 0

    // ================= Phase B: attn (normalized) + PV =================
    f32x4 vr[4];
    #pragma unroll
    for (int u = 0; u < 4; ++u) { kr[u] = ((const f32x4*)kst)[u]; vr[u] = ((const f32x4*)vst)[u]; }
    er0 = *(const f32x4*)est; er1 = *(const f32x4*)(est + 4);
    #pragma unroll
    for (int jt = 0; jt < 4; ++jt)
        mv[jt] = *(const i32x4*)(mrow + jt * 16 + quad * 4);

    f32x4 cacc[4] = { {0,0,0,0}, {0,0,0,0}, {0,0,0,0}, {0,0,0,0} };

    for (int jb = 0; jb < 32; ++jb) {
        const int j0 = jb * 64;
        // stage current tile from prefetched regs: K[bb], V^T[bb], edge slot0
        {
            char* kb = lds + bb * 8192;
            char* vb = lds + 16384 + bb * 8192;
            #pragma unroll
            for (int u = 0; u < 4; ++u) {
                *(short4*)SWZ(kb, r, 2 * seg + 8 * u) =
                    make_short4(f2bf(kr[u][0]), f2bf(kr[u][1]), f2bf(kr[u][2]), f2bf(kr[u][3]));
                // V transpose: Vt[ch][j] (R10-style scalar b16 writes, swizzled rows)
                *(short*)SWZ(vb, seg + u * 4 + 0, r * 2) = f2bf(vr[u][0]);
                *(short*)SWZ(vb, seg + u * 4 + 1, r * 2) = f2bf(vr[u][1]);
                *(short*)SWZ(vb, seg + u * 4 + 2, r * 2) = f2bf(vr[u][2]);
                *(short*)SWZ(vb, seg + u * 4 + 3, r * 2) = f2bf(vr[u][3]);
            }
            *(f32x4*)EDGE_AT(EDGE_LDS(0), erow_st, ecol_st) = er0;
            *(f32x4*)EDGE_AT(EDGE_LDS(0), erow_st, ecol_st + 4) = er1;
        }
        lds_barrier();                 // writes visible; NO global drain

        char* const kb = lds + wb * 8192;
        f32x4 acc[4];                  // identical MFMA as phase A -> bitwise-same s4
        #pragma unroll
        for (int jt = 0; jt < 4; ++jt) {
            bf16x8 kf0 = *(const bf16x8*)SWZ(kb, jt * 16 + mm, 16 * quad);
            bf16x8 kf1 = *(const bf16x8*)SWZ(kb, jt * 16 + mm, 64 + 16 * quad);
            f32x4 a = {0.f, 0.f, 0.f, 0.f};
            a = __builtin_amdgcn_mfma_f32_16x16x32_bf16(kf0, qa0, a, 0, 0, 0);
            a = __builtin_amdgcn_mfma_f32_16x16x32_bf16(kf1, qa1, a, 0, 0, 0);
            acc[jt] = a;
        }

        if (jb < 31) {                 // issue next K/V/edge (in flight across barriers)
            const float* kp = kst + kstep * (jb + 1);
            const float* vp = vst + kstep * (jb + 1);
            #pragma unroll
            for (int u = 0; u < 4; ++u) { kr[u] = ((const f32x4*)kp)[u]; vr[u] = ((const f32x4*)vp)[u]; }
            er0 = *(const f32x4*)(est + (size_t)(jb + 1) * 64);
            er1 = *(const f32x4*)(est + (size_t)(jb + 1) * 64 + 4);
        }

        // epilogue: attn = normalized w, Wt = bf16(w) for PV
        char* const eb = EDGE_LDS(0);
        #pragma unroll
        for (int jt = 0; jt < 4; ++jt) {
            f32x4 ev = *(const f32x4*)EDGE_AT(eb, wrow * 16 + mm, jt * 16 + quad * 4);
            f32x4 s4 = acc[jt] + ev;
            f32x4 w;
            w[0] = mv[jt][0] ? __expf(s4[0] * 0.125f) * inv : 0.f;
            w[1] = mv[jt][1] ? __expf(s4[1] * 0.125f) * inv : 0.f;
            w[2] = mv[jt][2] ? __expf(s4[2] * 0.125f) * inv : 0.f;
            w[3] = mv[jt][3] ? __expf(s4[3] * 0.125f) * inv : 0.f;
            *(f32x4*)(attn + srow + j0 + jt * 16 + quad * 4) = w;
            *(short4*)SWZ(wtb, mm, 32 * jt + 8 * quad) =
                make_short4(f2bf(w[0]), f2bf(w[1]), f2bf(w[2]), f2bf(w[3]));
        }

        if (jb < 31) {   // mask 1-ahead
            #pragma unroll
            for (int jt = 0; jt < 4; ++jt)
                mv[jt] = *(const i32x4*)(mrow + j0 + 64 + jt * 16 + quad * 4);
        }

        // PV: A = Wt row mm (wave-internal RAW), B = V^T[wb].
        char* const vb = lds + 16384 + wb * 8192;
        #pragma unroll
        for (int kt = 0; kt < 2; ++kt) {
            bf16x8 aw = *(const bf16x8*)SWZ(wtb, mm, 64 * kt + 16 * quad);
            #pragma unroll
            for (int nt = 0; nt < 4; ++nt) {
                bf16x8 bbv = *(const bf16x8*)SWZ(vb, nt * 16 + mm, 64 * kt + 16 * quad);
                cacc[nt] = __builtin_amdgcn_mfma_f32_16x16x32_bf16(aw, bbv, cacc[nt], 0, 0, 0);
            }
        }
        lds_barrier();                 // readers done; next iter may overwrite
    }

    // ctx: C-layout (col c = nt*16+mm, row i = quad*4+reg); already normalized
    const int irow = i0 + wrow * 16 + quad * 4;
    #pragma unroll
    for (int nt = 0; nt < 4; ++nt) {
        const int c = nt * 16 + mm;
        #pragma unroll
        for (int reg = 0; reg < 4; ++reg) {
            const int i = irow + reg;
            ctx[((size_t)(wb * LQ + i)) * NHC + h * CD + c] = cacc[nt][reg];
        }
    }
}

extern "C" void kernel_launch(void* const* d_in, const int* in_sizes, int n_in,
                              void* d_out, int out_size, void* d_ws, size_t ws_size,
                              hipStream_t stream) {
    const float* q    = (const float*)d_in[0];
    const float* k    = (const float*)d_in[1];
    const float* v    = (const float*)d_in[2];
    const int*   mask = (const int*)d_in[3];    // bool -> int32 per harness contract
    const float* edge = (const float*)d_in[4];

    float* out = (float*)d_out;
    float* ctx = out;                            // 2*2048*1024
    float* sc  = out + 4194304;                  // scores (B,H,L,L)
    float* at  = sc + 134217728;                 // attn   (B,H,L,L)

    k_attn<<<dim3(512), 512, 0, stream>>>(q, k, v, mask, edge, sc, at, ctx);
}